// Round 1
// baseline (927.641 us; speedup 1.0000x reference)
//
#include <hip/hip_runtime.h>

// RNN: h_{t+1} = tanh(W h_t + w_bias + V x_t + v_bias)
// x: [S,B,I] f32; W: [H,H]; V: [H,I]; out = h_seq [S,B,H] ++ h_final [B,H]
// S=2048 B=2048 I=16 H=64.
//
// Mapping: 1 wave (64 lanes) per batch row. Lane j owns hidden unit j:
//  - W row j (64 f32) and V row j (16 f32) in registers (loaded once)
//  - h vector in wave-private LDS (256 B), re-read each step as broadcast
//    ds_read_b128 (all lanes same address -> conflict-free)
//  - x staged in wave-private LDS in 64-step chunks (no barriers needed)
//  - tanh via exp2+rcp: tanh(p) = 1 - 2/(exp2(p*2*log2e)+1)

constexpr int S = 2048, B = 2048, I = 16, H = 64;
constexpr int CH = 64;  // timesteps of x staged per chunk

__global__ __launch_bounds__(64, 2)
void rnn_fused(const float* __restrict__ x,
               const float* __restrict__ Wm,
               const float* __restrict__ wb,
               const float* __restrict__ Vm,
               const float* __restrict__ vb,
               float* __restrict__ out)
{
    const int j = threadIdx.x;   // 0..63 = hidden unit
    const int b = blockIdx.x;    // batch row

    __shared__ __align__(16) float xs[CH][I];  // 4 KB, wave-private
    __shared__ __align__(16) float hs[H];      // 256 B, wave-private

    // ---- load per-lane weight rows (held in VGPRs for the whole kernel) ----
    float w[H];
#pragma unroll
    for (int c = 0; c < H / 4; ++c) {
        float4 t = *(const float4*)(Wm + j * H + c * 4);
        w[c * 4 + 0] = t.x; w[c * 4 + 1] = t.y;
        w[c * 4 + 2] = t.z; w[c * 4 + 3] = t.w;
    }
    float v[I];
#pragma unroll
    for (int c = 0; c < I / 4; ++c) {
        float4 t = *(const float4*)(Vm + j * I + c * 4);
        v[c * 4 + 0] = t.x; v[c * 4 + 1] = t.y;
        v[c * 4 + 2] = t.z; v[c * 4 + 3] = t.w;
    }
    const float bias = wb[j] + vb[j];

    hs[j] = 0.0f;        // h0 = 0
    float h = 0.0f;

    float* op = out + (size_t)b * H + j;   // h_seq[t][b][j], stride B*H per t
    const float* xb = x + (size_t)b * I;   // x[t][b][i], stride B*I per t

    for (int t0 = 0; t0 < S; t0 += CH) {
        // ---- stage x[t0 .. t0+CH) for this batch row (wave-private LDS) ----
#pragma unroll
        for (int m = 0; m < (CH * I) / (4 * 64); ++m) {  // 4 float4 per lane
            int q = j + 64 * m;          // float4 index in [0, 256)
            int tl = q >> 2, i4 = q & 3;
            float4 t4 = *(const float4*)(xb + (size_t)(t0 + tl) * (B * I) + i4 * 4);
            *(float4*)(&xs[tl][i4 * 4]) = t4;
        }
        // (no barrier: LDS tile is private to this wave)

        for (int tt = 0; tt < CH; ++tt) {
            const float4* h4 = (const float4*)hs;
            float a0 = bias, a1 = 0.f, a2 = 0.f, a3 = 0.f;
            float a4 = 0.f, a5 = 0.f, a6 = 0.f, a7 = 0.f;
#pragma unroll
            for (int c = 0; c < 8; ++c) {   // 64 FMAs, 8 independent chains
                float4 u = h4[2 * c + 0];
                float4 z = h4[2 * c + 1];
                a0 = fmaf(u.x, w[8 * c + 0], a0);
                a1 = fmaf(u.y, w[8 * c + 1], a1);
                a2 = fmaf(u.z, w[8 * c + 2], a2);
                a3 = fmaf(u.w, w[8 * c + 3], a3);
                a4 = fmaf(z.x, w[8 * c + 4], a4);
                a5 = fmaf(z.y, w[8 * c + 5], a5);
                a6 = fmaf(z.z, w[8 * c + 6], a6);
                a7 = fmaf(z.w, w[8 * c + 7], a7);
            }
            // input projection V x_t (16 FMAs)
            const float4* x4 = (const float4*)xs[tt];
            float4 xa = x4[0], xbv = x4[1], xc = x4[2], xd = x4[3];
            a0 = fmaf(xa.x,  v[0],  a0);  a1 = fmaf(xa.y,  v[1],  a1);
            a2 = fmaf(xa.z,  v[2],  a2);  a3 = fmaf(xa.w,  v[3],  a3);
            a4 = fmaf(xbv.x, v[4],  a4);  a5 = fmaf(xbv.y, v[5],  a5);
            a6 = fmaf(xbv.z, v[6],  a6);  a7 = fmaf(xbv.w, v[7],  a7);
            a0 = fmaf(xc.x,  v[8],  a0);  a1 = fmaf(xc.y,  v[9],  a1);
            a2 = fmaf(xc.z,  v[10], a2);  a3 = fmaf(xc.w,  v[11], a3);
            a4 = fmaf(xd.x,  v[12], a4);  a5 = fmaf(xd.y,  v[13], a5);
            a6 = fmaf(xd.z,  v[14], a6);  a7 = fmaf(xd.w,  v[15], a7);

            float pre = ((a0 + a1) + (a2 + a3)) + ((a4 + a5) + (a6 + a7));

            // tanh(pre) = 1 - 2/(exp(2*pre)+1); exp via v_exp_f32 (exp2)
            float e = __builtin_amdgcn_exp2f(pre * 2.8853900817779268f);
            float r = __builtin_amdgcn_rcpf(e + 1.0f);
            h = fmaf(-2.0f, r, 1.0f);

            hs[j] = h;                               // feed next step
            op[(size_t)(t0 + tt) * (B * H)] = h;     // h_seq store, coalesced
        }
    }
    // final h (second tuple element), after h_seq
    out[(size_t)S * B * H + (size_t)b * H + j] = h;
}

extern "C" void kernel_launch(void* const* d_in, const int* in_sizes, int n_in,
                              void* d_out, int out_size, void* d_ws, size_t ws_size,
                              hipStream_t stream) {
    const float* x  = (const float*)d_in[0];
    const float* Wm = (const float*)d_in[1];
    const float* wb = (const float*)d_in[2];
    const float* Vm = (const float*)d_in[3];
    const float* vb = (const float*)d_in[4];
    float* out = (float*)d_out;

    rnn_fused<<<B, 64, 0, stream>>>(x, Wm, wb, Vm, vb, out);
}